// Round 7
// baseline (211.530 us; speedup 1.0000x reference)
//
#include <hip/hip_runtime.h>
#include <cstddef>

#define B_ 2
#define NQ_ 10000
#define C_ 256
#define M_ 8
#define L_ 3
#define K_ 4
#define D_ 32
#define P_ 13125   // 10000 + 2500 + 625

typedef unsigned short u16;
typedef __attribute__((ext_vector_type(8))) short short8;
typedef __attribute__((ext_vector_type(4))) float f32x4;

static __device__ __forceinline__ u16 f2bf(float f) {
    union { float f; unsigned u; } x; x.f = f;
    unsigned r = x.u + 0x7fffu + ((x.u >> 16) & 1u);   // RNE
    return (u16)(r >> 16);
}
static __device__ __forceinline__ float bf2f(u16 u) {
    union { unsigned u; float f; } x; x.u = (unsigned)u << 16;
    return x.f;
}
static __device__ __forceinline__ short8 cvt8(const float4& a, const float4& b) {
    short8 r;
    r[0] = (short)f2bf(a.x); r[1] = (short)f2bf(a.y);
    r[2] = (short)f2bf(a.z); r[3] = (short)f2bf(a.w);
    r[4] = (short)f2bf(b.x); r[5] = (short)f2bf(b.y);
    r[6] = (short)f2bf(b.z); r[7] = (short)f2bf(b.w);
    return r;
}

// ---------------------------------------------------------------------------
// Fused transpose + value projection:
//   proj[b, base+p, o] = sum_c V[b,c,p] * Wv[o,c] + bv[o]   (bf16 out)
// A staged via LDS transpose; both LDS arrays stride 264 u16 (16B-aligned ->
// ds_read_b128; bank base = row*4 mod 32 -> <=2-way, free).
// ---------------------------------------------------------------------------
__global__ __launch_bounds__(256) void proj_fused(
    const float* __restrict__ v0, const float* __restrict__ v1,
    const float* __restrict__ v2,
    const float* __restrict__ Wv, const float* __restrict__ bv,
    u16* __restrict__ proj)
{
    __shared__ u16 As[64 * 264];
    __shared__ u16 Bs[64 * 264];

    const int bid = blockIdx.x;
    const int rlo = bid & 7;
    const int tmp = bid >> 3;
    const int panel = tmp & 3;
    const int rowTile = (tmp >> 2) * 8 + rlo;
    if (rowTile >= 414) return;

    const int b  = rowTile / 207;
    const int tl = rowTile % 207;
    int lvl, p0, HW, base;
    if (tl < 157)      { lvl = 0; p0 = tl * 64;         HW = 10000; base = 0; }
    else if (tl < 197) { lvl = 1; p0 = (tl - 157) * 64; HW = 2500;  base = 10000; }
    else               { lvl = 2; p0 = (tl - 197) * 64; HW = 625;   base = 12500; }
    const float* V = (lvl == 0 ? v0 : (lvl == 1 ? v1 : v2)) + (size_t)b * 256 * HW;

    const int t = threadIdx.x;
    // stage A: thread covers px = t&63, channels ch0 + 4i (transpose in LDS)
    const int px  = t & 63;
    const int pxg = min(p0 + px, HW - 1);
    const int ch0 = t >> 6;
    #pragma unroll
    for (int g = 0; g < 8; ++g) {
        float vv[8];
        #pragma unroll
        for (int j = 0; j < 8; ++j)
            vv[j] = V[(size_t)(ch0 + 4 * (8 * g + j)) * HW + pxg];
        #pragma unroll
        for (int j = 0; j < 8; ++j)
            As[px * 264 + ch0 + 4 * (8 * g + j)] = f2bf(vv[j]);
    }
    // stage B: 64 cols x 256 k from f32 Wv, inline cvt
    const int o0 = panel * 64;
    #pragma unroll
    for (int i = 0; i < 8; ++i) {
        int idx = i * 256 + t;
        int col = idx >> 5;
        int kc  = (idx & 31) * 8;
        const float* Br = Wv + (size_t)(o0 + col) * 256 + kc;
        float4 f0 = *reinterpret_cast<const float4*>(Br);
        float4 f1 = *reinterpret_cast<const float4*>(Br + 4);
        *reinterpret_cast<short8*>(&Bs[col * 264 + kc]) = cvt8(f0, f1);
    }
    __syncthreads();

    const int w  = t >> 6;
    const int l  = t & 63;
    const int lr = l & 15;
    const int kb = (l >> 4) * 8;
    const int arow = w * 16 + lr;

    f32x4 acc[4] = {};
    #pragma unroll
    for (int k0 = 0; k0 < 256; k0 += 32) {
        short8 a  = *reinterpret_cast<const short8*>(&As[arow * 264 + kb + k0]);
        short8 b0 = *reinterpret_cast<const short8*>(&Bs[(0 * 16 + lr) * 264 + kb + k0]);
        short8 b1 = *reinterpret_cast<const short8*>(&Bs[(1 * 16 + lr) * 264 + kb + k0]);
        short8 b2 = *reinterpret_cast<const short8*>(&Bs[(2 * 16 + lr) * 264 + kb + k0]);
        short8 b3 = *reinterpret_cast<const short8*>(&Bs[(3 * 16 + lr) * 264 + kb + k0]);
        acc[0] = __builtin_amdgcn_mfma_f32_16x16x32_bf16(a, b0, acc[0], 0, 0, 0);
        acc[1] = __builtin_amdgcn_mfma_f32_16x16x32_bf16(a, b1, acc[1], 0, 0, 0);
        acc[2] = __builtin_amdgcn_mfma_f32_16x16x32_bf16(a, b2, acc[2], 0, 0, 0);
        acc[3] = __builtin_amdgcn_mfma_f32_16x16x32_bf16(a, b3, acc[3], 0, 0, 0);
    }

    const int orow = (l >> 4) * 4;
    #pragma unroll
    for (int ct = 0; ct < 4; ++ct) {
        const int col = o0 + ct * 16 + lr;
        const float bsv = bv[col];
        #pragma unroll
        for (int r = 0; r < 4; ++r) {
            const int prow = w * 16 + orow + r;
            if (p0 + prow < HW)
                proj[((size_t)b * P_ + base + p0 + prow) * 256 + col] =
                    f2bf(acc[ct][r] + bsv);
        }
    }
}

// ---------------------------------------------------------------------------
// bf16 MFMA GEMM. A fragments for the whole K prefetched into registers
// BEFORE B-staging + barrier; k-loop is pure LDS+MFMA. B staged from f32
// with inline cvt. XCD-aware 1-D grid.
// ---------------------------------------------------------------------------
template <bool AF32, typename OutT>
__global__ __launch_bounds__(256) void gemm_panel(
    const void* __restrict__ Av, int rows, int nRowTiles, int npanel,
    const float* __restrict__ B1f, const float* __restrict__ bias1, int N1,
    const float* __restrict__ B2f, const float* __restrict__ bias2, int Ntot,
    OutT* __restrict__ Cout)
{
    __shared__ u16 Bs[64 * 264];

    const int bid  = blockIdx.x;
    const int rlo  = bid & 7;
    const int tmp  = bid >> 3;
    const int panel = tmp % npanel;
    const int rowTile = (tmp / npanel) * 8 + rlo;
    if (rowTile >= nRowTiles) return;

    const int t  = threadIdx.x;
    const int w  = t >> 6;
    const int l  = t & 63;
    const int row0 = rowTile * 128 + w * 32;
    const int o0   = panel * 64;
    const int lr = l & 15;
    const int kb = (l >> 4) * 8;

    const int ra0 = min(row0 + lr,      rows - 1);
    const int ra1 = min(row0 + 16 + lr, rows - 1);

    // ---- A prefetch: entire K for this thread's 2 fragment rows ----
    short8 a0r[8], a1r[8];
    if constexpr (AF32) {
        const float* Af  = (const float*)Av;
        const float* Ap0 = Af + (size_t)ra0 * 256 + kb;
        const float* Ap1 = Af + (size_t)ra1 * 256 + kb;
        #pragma unroll
        for (int s = 0; s < 8; ++s) {
            float4 x0 = *reinterpret_cast<const float4*>(Ap0 + s * 32);
            float4 y0 = *reinterpret_cast<const float4*>(Ap0 + s * 32 + 4);
            float4 x1 = *reinterpret_cast<const float4*>(Ap1 + s * 32);
            float4 y1 = *reinterpret_cast<const float4*>(Ap1 + s * 32 + 4);
            a0r[s] = cvt8(x0, y0);
            a1r[s] = cvt8(x1, y1);
        }
    } else {
        const u16* Af  = (const u16*)Av;
        const u16* Ap0 = Af + (size_t)ra0 * 256 + kb;
        const u16* Ap1 = Af + (size_t)ra1 * 256 + kb;
        #pragma unroll
        for (int s = 0; s < 8; ++s) {
            a0r[s] = *reinterpret_cast<const short8*>(Ap0 + s * 32);
            a1r[s] = *reinterpret_cast<const short8*>(Ap1 + s * 32);
        }
    }

    // ---- B staging: 64 cols x 256 k, f32 -> bf16 ----
    #pragma unroll
    for (int i = 0; i < 8; ++i) {
        int idx = i * 256 + t;
        int col = idx >> 5;
        int kc  = (idx & 31) * 8;
        int colg = min(o0 + col, Ntot - 1);
        const float* Br = ((colg < N1) ? B1f + (size_t)colg * 256
                                       : B2f + (size_t)(colg - N1) * 256) + kc;
        float4 f0 = *reinterpret_cast<const float4*>(Br);
        float4 f1 = *reinterpret_cast<const float4*>(Br + 4);
        *reinterpret_cast<short8*>(&Bs[col * 264 + kc]) = cvt8(f0, f1);
    }
    __syncthreads();

    f32x4 acc[2][4] = {};

    #pragma unroll
    for (int s = 0; s < 8; ++s) {
        const int k0 = s * 32;
        short8 b0 = *reinterpret_cast<const short8*>(&Bs[(0 * 16 + lr) * 264 + kb + k0]);
        short8 b1 = *reinterpret_cast<const short8*>(&Bs[(1 * 16 + lr) * 264 + kb + k0]);
        short8 b2 = *reinterpret_cast<const short8*>(&Bs[(2 * 16 + lr) * 264 + kb + k0]);
        short8 b3 = *reinterpret_cast<const short8*>(&Bs[(3 * 16 + lr) * 264 + kb + k0]);
        acc[0][0] = __builtin_amdgcn_mfma_f32_16x16x32_bf16(a0r[s], b0, acc[0][0], 0, 0, 0);
        acc[0][1] = __builtin_amdgcn_mfma_f32_16x16x32_bf16(a0r[s], b1, acc[0][1], 0, 0, 0);
        acc[0][2] = __builtin_amdgcn_mfma_f32_16x16x32_bf16(a0r[s], b2, acc[0][2], 0, 0, 0);
        acc[0][3] = __builtin_amdgcn_mfma_f32_16x16x32_bf16(a0r[s], b3, acc[0][3], 0, 0, 0);
        acc[1][0] = __builtin_amdgcn_mfma_f32_16x16x32_bf16(a1r[s], b0, acc[1][0], 0, 0, 0);
        acc[1][1] = __builtin_amdgcn_mfma_f32_16x16x32_bf16(a1r[s], b1, acc[1][1], 0, 0, 0);
        acc[1][2] = __builtin_amdgcn_mfma_f32_16x16x32_bf16(a1r[s], b2, acc[1][2], 0, 0, 0);
        acc[1][3] = __builtin_amdgcn_mfma_f32_16x16x32_bf16(a1r[s], b3, acc[1][3], 0, 0, 0);
    }

    const int orow = (l >> 4) * 4;
    #pragma unroll
    for (int ct = 0; ct < 4; ++ct) {
        const int col = o0 + ct * 16 + lr;
        if (col >= Ntot) continue;
        const float bsv = (col < N1) ? bias1[col] : bias2[col - N1];
        #pragma unroll
        for (int rt = 0; rt < 2; ++rt) {
            #pragma unroll
            for (int r = 0; r < 4; ++r) {
                const int row = row0 + rt * 16 + orow + r;
                if (row < rows) {
                    float val = acc[rt][ct][r] + bsv;
                    if constexpr (sizeof(OutT) == 2)
                        Cout[(size_t)row * Ntot + col] = (OutT)f2bf(val);
                    else
                        Cout[(size_t)row * Ntot + col] = (OutT)val;
                }
            }
        }
    }
}

// ---------------------------------------------------------------------------
// Sampling v3: 4 queries/block. Phase 1: 384 meta entries (corner idx +
// premultiplied weights) -> LDS, grid-stride over 256 threads. Phase 2:
// thread = (q = t>>6, head = (t>>3)&7, chan-group of 4 = t&7); each corner
// read is one 8 B uint2 (4 bf16 channels) -> 512 useful B per wave-load.
// ---------------------------------------------------------------------------
__global__ __launch_bounds__(256) void sample_kernel(
    const u16* __restrict__ S,         // [B*NQ, 288] bf16
    const float* __restrict__ refp,    // [B*NQ, 2]
    const u16* __restrict__ proj,      // [B, P_, 256] bf16
    u16* __restrict__ out2)            // [B*NQ, 256] bf16
{
    constexpr int Wd[3]   = {100, 50, 25};
    constexpr int offs[3] = {0, 10000, 12500};

    __shared__ int   midx[384][4];
    __shared__ float mw[384][4];

    const int t = threadIdx.x;

    for (int e = t; e < 384; e += 256) {
        const int q  = e / 96;
        const int tq = e % 96;
        const int tm = tq / 12;
        const int tj = tq % 12;
        const int bq = blockIdx.x * 4 + q;
        const u16* Sq = S + (size_t)bq * 288;

        float lg[12], mx = -1e30f;
        #pragma unroll
        for (int jj = 0; jj < 12; ++jj) {
            lg[jj] = bf2f(Sq[192 + tm * 12 + jj]);
            mx = fmaxf(mx, lg[jj]);
        }
        float sum = 0.f;
        #pragma unroll
        for (int jj = 0; jj < 12; ++jj) sum += __expf(lg[jj] - mx);
        const float attn = __expf(lg[tj] - mx) / sum;

        const int l  = tj >> 2;
        const int Wl = Wd[l];
        const float refx = refp[(size_t)bq * 2 + 0];
        const float refy = refp[(size_t)bq * 2 + 1];
        const float ox = bf2f(Sq[(tm * 12 + tj) * 2 + 0]);
        const float oy = bf2f(Sq[(tm * 12 + tj) * 2 + 1]);
        const float px = refx * (float)Wl + ox - 0.5f;   // H==W per level
        const float py = refy * (float)Wl + oy - 0.5f;
        const float x0f = floorf(px), y0f = floorf(py);
        const float wx1 = px - x0f, wy1 = py - y0f;
        const float wx0 = 1.f - wx1, wy0 = 1.f - wy1;
        const int x0 = (int)x0f, y0 = (int)y0f;
        const int x1 = x0 + 1, y1 = y0 + 1;
        const bool vx0 = (unsigned)x0 < (unsigned)Wl;
        const bool vx1 = (unsigned)x1 < (unsigned)Wl;
        const bool vy0 = (unsigned)y0 < (unsigned)Wl;
        const bool vy1 = (unsigned)y1 < (unsigned)Wl;
        const int chb  = tm * 32;
        const int base = offs[l];
        midx[e][0] = (vx0 && vy0) ? ((base + y0 * Wl + x0) * 256 + chb) : 0;
        midx[e][1] = (vx1 && vy0) ? ((base + y0 * Wl + x1) * 256 + chb) : 0;
        midx[e][2] = (vx0 && vy1) ? ((base + y1 * Wl + x0) * 256 + chb) : 0;
        midx[e][3] = (vx1 && vy1) ? ((base + y1 * Wl + x1) * 256 + chb) : 0;
        mw[e][0] = (vx0 && vy0) ? attn * wx0 * wy0 : 0.f;
        mw[e][1] = (vx1 && vy0) ? attn * wx1 * wy0 : 0.f;
        mw[e][2] = (vx0 && vy1) ? attn * wx0 * wy1 : 0.f;
        mw[e][3] = (vx1 && vy1) ? attn * wx1 * wy1 : 0.f;
    }
    __syncthreads();

    const int qi  = t >> 6;           // 0..3
    const int r   = t & 63;
    const int mh  = r >> 3;           // head 0..7
    const int d8  = r & 7;            // channel group of 4
    const int bq2 = blockIdx.x * 4 + qi;
    const int b   = bq2 / NQ_;
    const u16* projb = proj + (size_t)b * P_ * 256 + 4 * d8;

    float a0 = 0.f, a1 = 0.f, a2 = 0.f, a3 = 0.f;

    #pragma unroll
    for (int j = 0; j < 12; ++j) {
        const int mj = qi * 96 + mh * 12 + j;
        const int4   o  = *reinterpret_cast<const int4*>(midx[mj]);
        const float4 ww = *reinterpret_cast<const float4*>(mw[mj]);
        const int* op = &o.x;
        const float* wp = &ww.x;
        #pragma unroll
        for (int c = 0; c < 4; ++c) {
            const uint2 u = *reinterpret_cast<const uint2*>(projb + op[c]);
            const float wgt = wp[c];
            union { unsigned q; float f; } e0, e1, e2, e3;
            e0.q = u.x << 16; e1.q = u.x & 0xffff0000u;
            e2.q = u.y << 16; e3.q = u.y & 0xffff0000u;
            a0 = fmaf(wgt, e0.f, a0);
            a1 = fmaf(wgt, e1.f, a1);
            a2 = fmaf(wgt, e2.f, a2);
            a3 = fmaf(wgt, e3.f, a3);
        }
    }

    uint2 p;
    p.x = (unsigned)f2bf(a0) | ((unsigned)f2bf(a1) << 16);
    p.y = (unsigned)f2bf(a2) | ((unsigned)f2bf(a3) << 16);
    *reinterpret_cast<uint2*>(out2 + (size_t)bq2 * 256 + mh * 32 + 4 * d8) = p;
}

// ---------------------------------------------------------------------------
extern "C" void kernel_launch(void* const* d_in, const int* in_sizes, int n_in,
                              void* d_out, int out_size, void* d_ws, size_t ws_size,
                              hipStream_t stream)
{
    const float* query = (const float*)d_in[0];
    const float* refp  = (const float*)d_in[1];
    const float* v0    = (const float*)d_in[2];
    const float* v1    = (const float*)d_in[3];
    const float* v2    = (const float*)d_in[4];
    const float* Wv    = (const float*)d_in[5];
    const float* bv    = (const float*)d_in[6];
    const float* Ws    = (const float*)d_in[7];
    const float* bs    = (const float*)d_in[8];
    const float* Wa    = (const float*)d_in[9];
    const float* ba    = (const float*)d_in[10];
    const float* Wo    = (const float*)d_in[11];
    const float* bo    = (const float*)d_in[12];
    float* out = (float*)d_out;

    char* wsb = (char*)d_ws;
    u16*   proj = (u16*)wsb;    wsb += (size_t)B_ * P_ * 256 * 2;   // 13.44 MB
    u16*   S    = (u16*)wsb;    wsb += (size_t)B_ * NQ_ * 288 * 2;  // 11.52 MB
    u16*   out2 = (u16*)wsb;    wsb += (size_t)B_ * NQ_ * 256 * 2;  // 10.24 MB

    dim3 blk(256);

    // 1) fused transpose + value projection -> proj bf16
    proj_fused<<<dim3(1664), blk, 0, stream>>>(v0, v1, v2, Wv, bv, proj);

    // 2) offsets+logits -> S bf16 (A = query f32, in-register cvt)
    gemm_panel<true, u16><<<dim3(800), blk, 0, stream>>>(
        query, B_ * NQ_, 157, 5, Ws, bs, 192, Wa, ba, 288, S);

    // 3) softmax + bilinear sampling -> out2 bf16 (4 queries/block)
    sample_kernel<<<dim3(NQ_ * B_ / 4), blk, 0, stream>>>(S, refp, proj, out2);

    // 4) output projection -> d_out f32
    gemm_panel<false, float><<<dim3(640), blk, 0, stream>>>(
        out2, B_ * NQ_, 157, 4, Wo, bo, 256, Wo, bo, 256, out);
}

// Round 8
// 206.105 us; speedup vs baseline: 1.0263x; 1.0263x over previous
//
#include <hip/hip_runtime.h>
#include <cstddef>

#define B_ 2
#define NQ_ 10000
#define C_ 256
#define M_ 8
#define L_ 3
#define K_ 4
#define D_ 32
#define P_ 13125   // 10000 + 2500 + 625

typedef unsigned short u16;
typedef __attribute__((ext_vector_type(8))) short short8;
typedef __attribute__((ext_vector_type(4))) float f32x4;

static __device__ __forceinline__ u16 f2bf(float f) {
    union { float f; unsigned u; } x; x.f = f;
    unsigned r = x.u + 0x7fffu + ((x.u >> 16) & 1u);   // RNE
    return (u16)(r >> 16);
}
static __device__ __forceinline__ short8 cvt8(const float4& a, const float4& b) {
    short8 r;
    r[0] = (short)f2bf(a.x); r[1] = (short)f2bf(a.y);
    r[2] = (short)f2bf(a.z); r[3] = (short)f2bf(a.w);
    r[4] = (short)f2bf(b.x); r[5] = (short)f2bf(b.y);
    r[6] = (short)f2bf(b.z); r[7] = (short)f2bf(b.w);
    return r;
}

// ---------------------------------------------------------------------------
// query f32 -> bf16, 4/thread. 20000*256 elems -> 5000 blocks.
// ---------------------------------------------------------------------------
__global__ __launch_bounds__(256) void cvt_q(
    const float* __restrict__ src, u16* __restrict__ dst)
{
    const int i4 = (blockIdx.x * 256 + threadIdx.x) * 4;
    float4 v = *reinterpret_cast<const float4*>(src + i4);
    ushort4 o;
    o.x = f2bf(v.x); o.y = f2bf(v.y); o.z = f2bf(v.z); o.w = f2bf(v.w);
    *reinterpret_cast<ushort4*>(dst + i4) = o;
}

// ---------------------------------------------------------------------------
// Fused transpose + value projection, A-resident multi-panel:
//   proj[b, base+p, o] = sum_c V[b,c,p] * Wv[o,c] + bv[o]   (bf16 out)
// Block = one 64-pixel tile. A transposed to LDS ONCE, A-frags prefetched to
// registers, then 4 B panels staged+MFMA'd in-block. K-loop per panel:
// 4 ds_read_b128 -> 4 MFMA (A from regs).
// ---------------------------------------------------------------------------
__global__ __launch_bounds__(256) void proj_fused(
    const float* __restrict__ v0, const float* __restrict__ v1,
    const float* __restrict__ v2,
    const float* __restrict__ Wv, const float* __restrict__ bv,
    u16* __restrict__ proj)
{
    __shared__ u16 As[64 * 264];
    __shared__ u16 Bs[64 * 264];

    const int rowTile = blockIdx.x;      // 0..413
    const int b  = rowTile / 207;
    const int tl = rowTile % 207;
    int p0, HW, base;
    const float* V;
    if (tl < 157)      { p0 = tl * 64;         HW = 10000; base = 0;
                         V = v0 + (size_t)b * 256 * 10000; }
    else if (tl < 197) { p0 = (tl - 157) * 64; HW = 2500;  base = 10000;
                         V = v1 + (size_t)b * 256 * 2500; }
    else               { p0 = (tl - 197) * 64; HW = 625;   base = 12500;
                         V = v2 + (size_t)b * 256 * 625; }

    const int t = threadIdx.x;
    // stage A (transpose): thread covers px = t&63, channels ch0 + 4i
    const int px  = t & 63;
    const int pxg = min(p0 + px, HW - 1);
    const int ch0 = t >> 6;
    #pragma unroll
    for (int g = 0; g < 8; ++g) {
        float vv[8];
        #pragma unroll
        for (int j = 0; j < 8; ++j)
            vv[j] = V[(size_t)(ch0 + 4 * (8 * g + j)) * HW + pxg];
        #pragma unroll
        for (int j = 0; j < 8; ++j)
            As[px * 264 + ch0 + 4 * (8 * g + j)] = f2bf(vv[j]);
    }
    __syncthreads();

    const int w  = t >> 6;
    const int l  = t & 63;
    const int lr = l & 15;
    const int kb = (l >> 4) * 8;
    const int arow = w * 16 + lr;

    // prefetch A fragments to registers (reused across all 4 panels)
    short8 a[8];
    #pragma unroll
    for (int s = 0; s < 8; ++s)
        a[s] = *reinterpret_cast<const short8*>(&As[arow * 264 + kb + s * 32]);

    for (int p = 0; p < 4; ++p) {
        __syncthreads();   // previous panel's Bs readers done
        const int o0 = p * 64;
        #pragma unroll
        for (int i = 0; i < 8; ++i) {
            int idx = i * 256 + t;
            int col = idx >> 5;
            int kc  = (idx & 31) * 8;
            const float* Br = Wv + (size_t)(o0 + col) * 256 + kc;
            float4 f0 = *reinterpret_cast<const float4*>(Br);
            float4 f1 = *reinterpret_cast<const float4*>(Br + 4);
            *reinterpret_cast<short8*>(&Bs[col * 264 + kc]) = cvt8(f0, f1);
        }
        __syncthreads();

        f32x4 acc[4] = {};
        #pragma unroll
        for (int s = 0; s < 8; ++s) {
            const int k0 = s * 32;
            short8 b0 = *reinterpret_cast<const short8*>(&Bs[(0 * 16 + lr) * 264 + kb + k0]);
            short8 b1 = *reinterpret_cast<const short8*>(&Bs[(1 * 16 + lr) * 264 + kb + k0]);
            short8 b2 = *reinterpret_cast<const short8*>(&Bs[(2 * 16 + lr) * 264 + kb + k0]);
            short8 b3 = *reinterpret_cast<const short8*>(&Bs[(3 * 16 + lr) * 264 + kb + k0]);
            acc[0] = __builtin_amdgcn_mfma_f32_16x16x32_bf16(a[s], b0, acc[0], 0, 0, 0);
            acc[1] = __builtin_amdgcn_mfma_f32_16x16x32_bf16(a[s], b1, acc[1], 0, 0, 0);
            acc[2] = __builtin_amdgcn_mfma_f32_16x16x32_bf16(a[s], b2, acc[2], 0, 0, 0);
            acc[3] = __builtin_amdgcn_mfma_f32_16x16x32_bf16(a[s], b3, acc[3], 0, 0, 0);
        }

        const int orow = (l >> 4) * 4;
        #pragma unroll
        for (int ct = 0; ct < 4; ++ct) {
            const int col = o0 + ct * 16 + lr;
            const float bsv = bv[col];
            #pragma unroll
            for (int r = 0; r < 4; ++r) {
                const int prow = w * 16 + orow + r;
                if (p0 + prow < HW)
                    proj[((size_t)b * P_ + base + p0 + prow) * 256 + col] =
                        f2bf(acc[ct][r] + bsv);
            }
        }
    }
}

// ---------------------------------------------------------------------------
// bf16 MFMA GEMM, wave-M = 64 (A fully in registers: a[4][8] short8).
// Block tile 256 rows x 64 cols; 4 waves, each 64 rows x 64 cols, acc 4x4.
// K-loop: 4 ds_read_b128 (B) -> 16 MFMA. grid = nRowTiles * npanel.
// ---------------------------------------------------------------------------
template <typename OutT>
__global__ __launch_bounds__(256) void gemm_reg(
    const u16* __restrict__ A, int rows, int npanel,
    const float* __restrict__ B1f, const float* __restrict__ bias1, int N1,
    const float* __restrict__ B2f, const float* __restrict__ bias2, int Ntot,
    OutT* __restrict__ Cout)
{
    __shared__ u16 Bs[64 * 264];

    const int rowTile = blockIdx.x / npanel;
    const int panel   = blockIdx.x % npanel;
    const int t  = threadIdx.x;
    const int w  = t >> 6;
    const int l  = t & 63;
    const int lr = l & 15;
    const int kb = (l >> 4) * 8;
    const int o0 = panel * 64;
    const int rbase = rowTile * 256 + w * 64;

    // A prefetch: 4 fragment rows x full K
    short8 a[4][8];
    #pragma unroll
    for (int f = 0; f < 4; ++f) {
        const int ra = min(rbase + f * 16 + lr, rows - 1);
        const u16* Ap = A + (size_t)ra * 256 + kb;
        #pragma unroll
        for (int s = 0; s < 8; ++s)
            a[f][s] = *reinterpret_cast<const short8*>(Ap + s * 32);
    }

    // B staging: 64 cols x 256 k, f32 -> bf16
    #pragma unroll
    for (int i = 0; i < 8; ++i) {
        int idx = i * 256 + t;
        int col = idx >> 5;
        int kc  = (idx & 31) * 8;
        int colg = min(o0 + col, Ntot - 1);
        const float* Br = ((colg < N1) ? B1f + (size_t)colg * 256
                                       : B2f + (size_t)(colg - N1) * 256) + kc;
        float4 f0 = *reinterpret_cast<const float4*>(Br);
        float4 f1 = *reinterpret_cast<const float4*>(Br + 4);
        *reinterpret_cast<short8*>(&Bs[col * 264 + kc]) = cvt8(f0, f1);
    }
    __syncthreads();

    f32x4 acc[4][4] = {};

    #pragma unroll
    for (int s = 0; s < 8; ++s) {
        const int k0 = s * 32;
        short8 b0 = *reinterpret_cast<const short8*>(&Bs[(0 * 16 + lr) * 264 + kb + k0]);
        short8 b1 = *reinterpret_cast<const short8*>(&Bs[(1 * 16 + lr) * 264 + kb + k0]);
        short8 b2 = *reinterpret_cast<const short8*>(&Bs[(2 * 16 + lr) * 264 + kb + k0]);
        short8 b3 = *reinterpret_cast<const short8*>(&Bs[(3 * 16 + lr) * 264 + kb + k0]);
        #pragma unroll
        for (int f = 0; f < 4; ++f) {
            acc[f][0] = __builtin_amdgcn_mfma_f32_16x16x32_bf16(a[f][s], b0, acc[f][0], 0, 0, 0);
            acc[f][1] = __builtin_amdgcn_mfma_f32_16x16x32_bf16(a[f][s], b1, acc[f][1], 0, 0, 0);
            acc[f][2] = __builtin_amdgcn_mfma_f32_16x16x32_bf16(a[f][s], b2, acc[f][2], 0, 0, 0);
            acc[f][3] = __builtin_amdgcn_mfma_f32_16x16x32_bf16(a[f][s], b3, acc[f][3], 0, 0, 0);
        }
    }

    const int orow = (l >> 4) * 4;
    #pragma unroll
    for (int ct = 0; ct < 4; ++ct) {
        const int col = o0 + ct * 16 + lr;
        if (col >= Ntot) continue;
        const float bsv = (col < N1) ? bias1[col] : bias2[col - N1];
        #pragma unroll
        for (int f = 0; f < 4; ++f) {
            #pragma unroll
            for (int r = 0; r < 4; ++r) {
                const int row = rbase + f * 16 + orow + r;
                if (row < rows) {
                    float val = acc[f][ct][r] + bsv;
                    if constexpr (sizeof(OutT) == 2)
                        Cout[(size_t)row * Ntot + col] = (OutT)f2bf(val);
                    else
                        Cout[(size_t)row * Ntot + col] = (OutT)val;
                }
            }
        }
    }
}

// ---------------------------------------------------------------------------
// Sampling: R6-proven structure (2 queries/block, 4 B uint bf16-pair loads,
// 2 channels/thread, S in f32). Phase 1 (threads 0..191): meta -> LDS.
// ---------------------------------------------------------------------------
__global__ __launch_bounds__(256) void sample_kernel(
    const float* __restrict__ S,       // [B*NQ, 288]
    const float* __restrict__ refp,    // [B*NQ, 2]
    const u16* __restrict__ proj,      // [B, P_, 256] bf16
    u16* __restrict__ out2)            // [B*NQ, 256] bf16
{
    constexpr int Wd[3]   = {100, 50, 25};
    constexpr int offs[3] = {0, 10000, 12500};

    __shared__ int   midx[192][4];
    __shared__ float mw[192][4];

    const int t = threadIdx.x;

    if (t < 192) {
        const int q  = t / 96;
        const int tq = t % 96;
        const int tm = tq / 12;
        const int tj = tq % 12;
        const int bq = blockIdx.x * 2 + q;
        const float* Sq = S + (size_t)bq * 288;

        float lg[12], mx = -1e30f;
        #pragma unroll
        for (int jj = 0; jj < 12; ++jj) {
            lg[jj] = Sq[192 + tm * 12 + jj];
            mx = fmaxf(mx, lg[jj]);
        }
        float sum = 0.f;
        #pragma unroll
        for (int jj = 0; jj < 12; ++jj) sum += __expf(lg[jj] - mx);
        const float attn = __expf(lg[tj] - mx) / sum;

        const int l  = tj >> 2;
        const int Wl = Wd[l];
        const float refx = refp[(size_t)bq * 2 + 0];
        const float refy = refp[(size_t)bq * 2 + 1];
        const float ox = Sq[(tm * 12 + tj) * 2 + 0];
        const float oy = Sq[(tm * 12 + tj) * 2 + 1];
        const float px = refx * (float)Wl + ox - 0.5f;   // H==W per level
        const float py = refy * (float)Wl + oy - 0.5f;
        const float x0f = floorf(px), y0f = floorf(py);
        const float wx1 = px - x0f, wy1 = py - y0f;
        const float wx0 = 1.f - wx1, wy0 = 1.f - wy1;
        const int x0 = (int)x0f, y0 = (int)y0f;
        const int x1 = x0 + 1, y1 = y0 + 1;
        const bool vx0 = (unsigned)x0 < (unsigned)Wl;
        const bool vx1 = (unsigned)x1 < (unsigned)Wl;
        const bool vy0 = (unsigned)y0 < (unsigned)Wl;
        const bool vy1 = (unsigned)y1 < (unsigned)Wl;
        const int chb  = tm * 32;
        const int base = offs[l];
        midx[t][0] = (vx0 && vy0) ? ((base + y0 * Wl + x0) * 256 + chb) : 0;
        midx[t][1] = (vx1 && vy0) ? ((base + y0 * Wl + x1) * 256 + chb) : 0;
        midx[t][2] = (vx0 && vy1) ? ((base + y1 * Wl + x0) * 256 + chb) : 0;
        midx[t][3] = (vx1 && vy1) ? ((base + y1 * Wl + x1) * 256 + chb) : 0;
        mw[t][0] = (vx0 && vy0) ? attn * wx0 * wy0 : 0.f;
        mw[t][1] = (vx1 && vy0) ? attn * wx1 * wy0 : 0.f;
        mw[t][2] = (vx0 && vy1) ? attn * wx0 * wy1 : 0.f;
        mw[t][3] = (vx1 && vy1) ? attn * wx1 * wy1 : 0.f;
    }
    __syncthreads();

    const int qi  = t >> 7;
    const int tt  = t & 127;
    const int mh  = tt >> 4;
    const int d16 = tt & 15;
    const int bq2 = blockIdx.x * 2 + qi;
    const int b   = bq2 / NQ_;
    const u16* projb = proj + (size_t)b * P_ * 256 + 2 * d16;

    float acc0 = 0.f, acc1 = 0.f;

    #pragma unroll
    for (int j = 0; j < 12; ++j) {
        const int mj = qi * 96 + mh * 12 + j;
        const int4   o  = *reinterpret_cast<const int4*>(midx[mj]);
        const float4 ww = *reinterpret_cast<const float4*>(mw[mj]);
        const unsigned u00 = *reinterpret_cast<const unsigned*>(projb + o.x);
        const unsigned u10 = *reinterpret_cast<const unsigned*>(projb + o.y);
        const unsigned u01 = *reinterpret_cast<const unsigned*>(projb + o.z);
        const unsigned u11 = *reinterpret_cast<const unsigned*>(projb + o.w);
        union { unsigned u; float f; } c0, c1;
        c0.u = u00 << 16;          c1.u = u00 & 0xffff0000u;
        acc0 = fmaf(ww.x, c0.f, acc0); acc1 = fmaf(ww.x, c1.f, acc1);
        c0.u = u10 << 16;          c1.u = u10 & 0xffff0000u;
        acc0 = fmaf(ww.y, c0.f, acc0); acc1 = fmaf(ww.y, c1.f, acc1);
        c0.u = u01 << 16;          c1.u = u01 & 0xffff0000u;
        acc0 = fmaf(ww.z, c0.f, acc0); acc1 = fmaf(ww.z, c1.f, acc1);
        c0.u = u11 << 16;          c1.u = u11 & 0xffff0000u;
        acc0 = fmaf(ww.w, c0.f, acc0); acc1 = fmaf(ww.w, c1.f, acc1);
    }

    const unsigned packed = (unsigned)f2bf(acc0) | ((unsigned)f2bf(acc1) << 16);
    *reinterpret_cast<unsigned*>(out2 + (size_t)bq2 * 256 + mh * 32 + 2 * d16) = packed;
}

// ---------------------------------------------------------------------------
extern "C" void kernel_launch(void* const* d_in, const int* in_sizes, int n_in,
                              void* d_out, int out_size, void* d_ws, size_t ws_size,
                              hipStream_t stream)
{
    const float* query = (const float*)d_in[0];
    const float* refp  = (const float*)d_in[1];
    const float* v0    = (const float*)d_in[2];
    const float* v1    = (const float*)d_in[3];
    const float* v2    = (const float*)d_in[4];
    const float* Wv    = (const float*)d_in[5];
    const float* bv    = (const float*)d_in[6];
    const float* Ws    = (const float*)d_in[7];
    const float* bs    = (const float*)d_in[8];
    const float* Wa    = (const float*)d_in[9];
    const float* ba    = (const float*)d_in[10];
    const float* Wo    = (const float*)d_in[11];
    const float* bo    = (const float*)d_in[12];
    float* out = (float*)d_out;

    char* wsb = (char*)d_ws;
    u16*   proj = (u16*)wsb;    wsb += (size_t)B_ * P_ * 256 * 2;   // 13.44 MB
    float* S    = (float*)wsb;  wsb += (size_t)B_ * NQ_ * 288 * 4;  // 23.04 MB
    u16*   out2 = (u16*)wsb;    wsb += (size_t)B_ * NQ_ * 256 * 2;  // 10.24 MB
    u16*   qbf  = (u16*)wsb;    wsb += (size_t)B_ * NQ_ * 256 * 2;  // 10.24 MB

    dim3 blk(256);

    // 0) query -> bf16
    cvt_q<<<dim3(5000), blk, 0, stream>>>(query, qbf);

    // 1) fused transpose + value projection (A-resident, 4 panels in-block)
    proj_fused<<<dim3(414), blk, 0, stream>>>(v0, v1, v2, Wv, bv, proj);

    // 2) offsets+logits -> S f32.  ceil(20000/256)=79 rowTiles x 5 panels
    gemm_reg<float><<<dim3(79 * 5), blk, 0, stream>>>(
        qbf, B_ * NQ_, 5, Ws, bs, 192, Wa, ba, 288, S);

    // 3) softmax + bilinear sampling -> out2 bf16 (R6 structure)
    sample_kernel<<<dim3(NQ_), blk, 0, stream>>>(S, refp, proj, out2);

    // 4) output projection -> d_out f32.  79 rowTiles x 4 panels
    gemm_reg<float><<<dim3(79 * 4), blk, 0, stream>>>(
        out2, B_ * NQ_, 4, Wo, bo, 256, Wo, bo, 256, out);
}